// Round 2
// 75.901 us; speedup vs baseline: 1.0055x; 1.0055x over previous
//
#include <hip/hip_runtime.h>

// Multinomial via sum tree. CAP=2^21 leaves, NSAMP=2^20 stratified samples.
// ws layout (floats):
//   [0      .. 8190 ]  plain tree slots; only 511..8190 (levels 9..12) written
//   [8192   .. 40959]  aux0: 4096 level-12 entries x 8 floats {v13,v14L,v14R,v15[0..3],pad}
//   [40960  .. 303103] aux1: 32768 level-15 entries x 8 floats {v16,v17L,v17R,v18[0..3],pad}
// Each 32B aux entry resolves 3 descent levels with one dependent fetch.
// Levels 19,20 + leaf comparisons come from an 8-leaf (32 B) prio load.
// Levels 0..8 are rebuilt per-block in LDS from staged level 9 (exact pairwise
// sums -> identical values in every block, bit-identical to reference tree).

#define CAP    (1 << 21)
#define NSAMP  (1 << 20)
#define L18OFF ((1 << 18) - 1)   // 262143
#define AUX0_F 8192              // float offset of aux0 in ws
#define AUX1_F 40960             // float offset of aux1 in ws

// ---- Build: 512 blocks x 256 threads; block owns 4096 leaves ------------
// Local heap H[1023]: H[0] = block's level-9 node ... H[511..1022] = level-18.
__global__ __launch_bounds__(256) void build_tree(const float* __restrict__ prio,
                                                  float* __restrict__ ws) {
    __shared__ __align__(16) float H[1023];
    const int b = blockIdx.x, t = threadIdx.x;
    const float4* p4 = (const float4*)(prio + (size_t)b * 4096);

    // level 18 (local lambda=9): each node = sum of 8 leaves, reference association.
    #pragma unroll
    for (int i = t; i < 512; i += 256) {
        float4 x = p4[2 * i], y = p4[2 * i + 1];
        H[511 + i] = ((x.x + x.y) + (x.z + x.w)) + ((y.x + y.y) + (y.z + y.w));
    }
    __syncthreads();
    // reduce lambda=8..0 (exact pairwise sums)
    for (int cnt = 256, off = 255; cnt >= 1; off >>= 1, cnt >>= 1) {
        for (int i = t; i < cnt; i += 256) {
            int h = off + i;
            H[h] = H[2 * h + 1] + H[2 * h + 2];
        }
        __syncthreads();
    }

    // plain tree writes: levels 9..12 (for sample-kernel LDS staging)
    if (t == 0)  ws[511 + b] = H[0];
    if (t < 2)   ws[1023 + 2 * b + t] = H[1 + t];
    if (t < 4)   ws[2047 + 4 * b + t] = H[3 + t];
    if (t < 8)   ws[4095 + 8 * b + t] = H[7 + t];

    // aux0: 8 level-12 entries/block, 8 floats each (64 floats, coalesced)
    if (t < 64) {
        int e = t >> 3, k = t & 7, h = 7 + e;
        float v;
        if      (k == 0) v = H[2 * h + 1];
        else if (k == 1) v = H[4 * h + 3];
        else if (k == 2) v = H[4 * h + 5];
        else if (k <  7) v = H[8 * h + 7 + 2 * (k - 3)];
        else             v = 0.0f;
        ws[AUX0_F + (size_t)b * 64 + t] = v;
    }
    // aux1: 64 level-15 entries/block, 8 floats each (512 floats, coalesced)
    #pragma unroll
    for (int i = t; i < 512; i += 256) {
        int e = i >> 3, k = i & 7, h = 63 + e;
        float v;
        if      (k == 0) v = H[2 * h + 1];
        else if (k == 1) v = H[4 * h + 3];
        else if (k == 2) v = H[4 * h + 5];
        else if (k <  7) v = H[8 * h + 7 + 2 * (k - 3)];
        else             v = 0.0f;
        ws[AUX1_F + (size_t)b * 512 + i] = v;
    }
}

// ---- Sample: 1024 blocks x 256 threads x 4 CONSECUTIVE samples/thread ----
__global__ __launch_bounds__(256) void sample_kernel(const float* __restrict__ ws,
                                                     const float* __restrict__ prio,
                                                     const float* __restrict__ uniform,
                                                     int* __restrict__ out) {
    __shared__ float nds[8191];          // nodes 0..8190 = levels 0..12 (32 KB)
    const int t = threadIdx.x;

    // stage levels 9..12 (slots 511..8190), coalesced
    for (int i = 511 + t; i < 8191; i += 256) nds[i] = ws[i];
    __syncthreads();
    // rebuild levels 8..0 in LDS (identical in every block; exact sums)
    {
        int cnt = 256, off = 255;
        for (int lvl = 8; lvl >= 0; --lvl) {
            for (int i = t; i < cnt; i += 256) {
                int n = off + i;
                nds[n] = nds[2 * n + 1] + nds[2 * n + 2];
            }
            __syncthreads();
            off = (off - 1) >> 1;
            cnt >>= 1;
        }
    }

    const float total = nds[0];
    const float scale = total / (float)NSAMP;     // exact pow-2 divide
    const int j0 = blockIdx.x * 1024 + t * 4;     // 4 consecutive samples

    float4 u4 = *(const float4*)(uniform + j0);
    float uu[4] = {u4.x, u4.y, u4.z, u4.w};

    float s[4];
    int   id[4];
    #pragma unroll
    for (int q = 0; q < 4; ++q) {
        int j = j0 + q;
        s[q]  = uu[q] * total / (float)NSAMP + scale * (float)j;  // == ref
        id[q] = 0;
    }

    // steps 0..11: levels 1..12 from LDS (4 near-identical chains -> broadcast)
    #pragma unroll
    for (int d = 0; d < 12; ++d) {
        #pragma unroll
        for (int q = 0; q < 4; ++q) {
            int left = 2 * id[q] + 1;
            float lv = nds[left];
            bool r = s[q] > lv;                   // ref: go_left = s <= lv
            s[q]  = r ? s[q] - lv : s[q];
            id[q] = r ? left + 1 : left;
        }
    }

    // levels 13..15 via one 32B aux0 fetch per chain (3 levels, 1 dependent step)
    {
        float4 A0[4], A1[4];
        #pragma unroll
        for (int q = 0; q < 4; ++q) {
            int l12 = id[q] - 4095;                       // level-12 position
            const float4* a = (const float4*)(ws + AUX0_F + (size_t)l12 * 8);
            A0[q] = a[0]; A1[q] = a[1];
        }
        #pragma unroll
        for (int q = 0; q < 4; ++q) {
            float ss = s[q];
            float v13 = A0[q].x;
            bool b0 = ss > v13; ss = b0 ? ss - v13 : ss;
            float v14 = b0 ? A0[q].z : A0[q].y;
            bool b1 = ss > v14; ss = b1 ? ss - v14 : ss;
            float v15 = b1 ? (b0 ? A1[q].z : A1[q].x)
                           : (b0 ? A1[q].y : A0[q].w);
            bool b2 = ss > v15; ss = b2 ? ss - v15 : ss;
            s[q]  = ss;
            id[q] = 8 * id[q] + 7 + (b0 ? 4 : 0) + (b1 ? 2 : 0) + (b2 ? 1 : 0);
        }
    }
    // levels 16..18 via one 32B aux1 fetch per chain
    {
        float4 A0[4], A1[4];
        #pragma unroll
        for (int q = 0; q < 4; ++q) {
            int l15 = id[q] - 32767;                      // level-15 position
            const float4* a = (const float4*)(ws + AUX1_F + (size_t)l15 * 8);
            A0[q] = a[0]; A1[q] = a[1];
        }
        #pragma unroll
        for (int q = 0; q < 4; ++q) {
            float ss = s[q];
            float v16 = A0[q].x;
            bool b0 = ss > v16; ss = b0 ? ss - v16 : ss;
            float v17 = b0 ? A0[q].z : A0[q].y;
            bool b1 = ss > v17; ss = b1 ? ss - v17 : ss;
            float v18 = b1 ? (b0 ? A1[q].z : A1[q].x)
                           : (b0 ? A1[q].y : A0[q].w);
            bool b2 = ss > v18; ss = b2 ? ss - v18 : ss;
            s[q]  = ss;
            id[q] = 8 * id[q] + 7 + (b0 ? 4 : 0) + (b1 ? 2 : 0) + (b2 ? 1 : 0);
        }
    }

    // bottom 3 levels from one 32 B leaf load, all in registers
    int res[4];
    #pragma unroll
    for (int q = 0; q < 4; ++q) {
        int p = id[q] - L18OFF;                       // level-18 position
        const float4* pp = (const float4*)prio + 2 * (size_t)p;
        float4 x = pp[0], y = pp[1];                  // leaves 8p..8p+7
        float l19 = (x.x + x.y) + (x.z + x.w);        // level-19 left child
        bool r1 = s[q] > l19;
        float ss = r1 ? s[q] - l19 : s[q];
        float l20 = r1 ? (y.x + y.y) : (x.x + x.y);   // level-20 left child
        bool r2 = ss > l20;
        ss = r2 ? ss - l20 : ss;
        float leaf = r1 ? (r2 ? y.z : y.x) : (r2 ? x.z : x.x);  // left leaf
        bool r3 = ss > leaf;
        res[q] = 8 * p + (r1 ? 4 : 0) + (r2 ? 2 : 0) + (r3 ? 1 : 0);
    }
    *(int4*)(out + j0) = make_int4(res[0], res[1], res[2], res[3]);
}

extern "C" void kernel_launch(void* const* d_in, const int* in_sizes, int n_in,
                              void* d_out, int out_size, void* d_ws, size_t ws_size,
                              hipStream_t stream) {
    const float* prio    = (const float*)d_in[0];   // [CAP]
    const float* uniform = (const float*)d_in[1];   // [NSAMP]
    (void)in_sizes; (void)n_in; (void)out_size; (void)ws_size;

    float* ws = (float*)d_ws;   // 303104 floats used (~1.16 MB)

    build_tree<<<512, 256, 0, stream>>>(prio, ws);
    sample_kernel<<<NSAMP / 1024, 256, 0, stream>>>(ws, prio, uniform, (int*)d_out);
}

// Round 3
// 75.438 us; speedup vs baseline: 1.0117x; 1.0061x over previous
//
#include <hip/hip_runtime.h>

// Multinomial via sum tree. CAP=2^21 leaves, NSAMP=2^20 stratified samples.
// ws layout (floats):
//   [0      .. 8190 ]  plain tree slots; only 511..8190 (levels 9..12) written
//   [8192   .. 40959]  aux0: 4096 level-12 entries x 8 floats {v13,v14L,v14R,v15[0..3],pad}
//   [40960  .. 303103] aux1: 32768 level-15 entries x 8 floats {v16,v17L,v17R,v18[0..3],pad}
// Each 32B aux entry resolves 3 descent levels with one dependent fetch.
// Levels 19,20 + leaf comparisons come from an 8-leaf (32 B) prio load.
// Levels 0..8 are rebuilt per-block in LDS (bit-identical to reference tree).
// Sample kernel: 512 blocks x 256 threads x 8 CONSECUTIVE samples/thread
// (halves per-block prologue redundancy vs 1024-block version; 8-chain ILP).

#define CAP    (1 << 21)
#define NSAMP  (1 << 20)
#define L18OFF ((1 << 18) - 1)   // 262143
#define AUX0_F 8192              // float offset of aux0 in ws
#define AUX1_F 40960             // float offset of aux1 in ws

// ---- Build: 512 blocks x 256 threads; block owns 4096 leaves ------------
// Local heap H[1023]: H[0] = block's level-9 node ... H[511..1022] = level-18.
__global__ __launch_bounds__(256) void build_tree(const float* __restrict__ prio,
                                                  float* __restrict__ ws) {
    __shared__ __align__(16) float H[1023];
    const int b = blockIdx.x, t = threadIdx.x;
    const float4* p4 = (const float4*)(prio + (size_t)b * 4096);

    // level 18: each node = sum of 8 leaves, reference association.
    #pragma unroll
    for (int i = t; i < 512; i += 256) {
        float4 x = p4[2 * i], y = p4[2 * i + 1];
        H[511 + i] = ((x.x + x.y) + (x.z + x.w)) + ((y.x + y.y) + (y.z + y.w));
    }
    __syncthreads();
    // reduce to level 9 (exact pairwise sums)
    for (int cnt = 256, off = 255; cnt >= 1; off >>= 1, cnt >>= 1) {
        for (int i = t; i < cnt; i += 256) {
            int h = off + i;
            H[h] = H[2 * h + 1] + H[2 * h + 2];
        }
        __syncthreads();
    }

    // plain tree writes: levels 9..12 (for sample-kernel LDS staging)
    if (t == 0)  ws[511 + b] = H[0];
    if (t < 2)   ws[1023 + 2 * b + t] = H[1 + t];
    if (t < 4)   ws[2047 + 4 * b + t] = H[3 + t];
    if (t < 8)   ws[4095 + 8 * b + t] = H[7 + t];

    // aux0: 8 level-12 entries/block, 8 floats each (64 floats, coalesced)
    if (t < 64) {
        int e = t >> 3, k = t & 7, h = 7 + e;
        float v;
        if      (k == 0) v = H[2 * h + 1];
        else if (k == 1) v = H[4 * h + 3];
        else if (k == 2) v = H[4 * h + 5];
        else if (k <  7) v = H[8 * h + 7 + 2 * (k - 3)];
        else             v = 0.0f;
        ws[AUX0_F + (size_t)b * 64 + t] = v;
    }
    // aux1: 64 level-15 entries/block, 8 floats each (512 floats, coalesced)
    #pragma unroll
    for (int i = t; i < 512; i += 256) {
        int e = i >> 3, k = i & 7, h = 63 + e;
        float v;
        if      (k == 0) v = H[2 * h + 1];
        else if (k == 1) v = H[4 * h + 3];
        else if (k == 2) v = H[4 * h + 5];
        else if (k <  7) v = H[8 * h + 7 + 2 * (k - 3)];
        else             v = 0.0f;
        ws[AUX1_F + (size_t)b * 512 + i] = v;
    }
}

// ---- Sample: 512 blocks x 256 threads x 8 consecutive samples/thread ----
__global__ __launch_bounds__(256) void sample_kernel(const float* __restrict__ ws,
                                                     const float* __restrict__ prio,
                                                     const float* __restrict__ uniform,
                                                     int* __restrict__ out) {
    __shared__ float nds[8191];          // nodes 0..8190 = levels 0..12 (32 KB)
    const int t = threadIdx.x;

    // stage levels 9..12 (slots 511..8190), coalesced
    for (int i = 511 + t; i < 8191; i += 256) nds[i] = ws[i];
    __syncthreads();
    // rebuild levels 8..0 in LDS (identical in every block; exact sums)
    {
        int cnt = 256, off = 255;
        for (int lvl = 8; lvl >= 0; --lvl) {
            for (int i = t; i < cnt; i += 256) {
                int n = off + i;
                nds[n] = nds[2 * n + 1] + nds[2 * n + 2];
            }
            __syncthreads();
            off = (off - 1) >> 1;
            cnt >>= 1;
        }
    }

    const float total = nds[0];
    const float scale = total / (float)NSAMP;     // exact pow-2 divide
    const int j0 = blockIdx.x * 2048 + t * 8;     // 8 consecutive samples

    float4 ua = *(const float4*)(uniform + j0);
    float4 ub = *(const float4*)(uniform + j0 + 4);
    float uu[8] = {ua.x, ua.y, ua.z, ua.w, ub.x, ub.y, ub.z, ub.w};

    float s[8];
    int   id[8];
    #pragma unroll
    for (int q = 0; q < 8; ++q) {
        int j = j0 + q;
        s[q]  = uu[q] * total / (float)NSAMP + scale * (float)j;  // == ref
        id[q] = 0;
    }

    // steps 0..11: levels 1..12 from LDS (8 near-identical chains -> broadcast)
    #pragma unroll
    for (int d = 0; d < 12; ++d) {
        #pragma unroll
        for (int q = 0; q < 8; ++q) {
            int left = 2 * id[q] + 1;
            float lv = nds[left];
            bool r = s[q] > lv;                   // ref: go_left = s <= lv
            s[q]  = r ? s[q] - lv : s[q];
            id[q] = r ? left + 1 : left;
        }
    }

    // levels 13..15 via one 32B aux0 fetch per chain (3 levels, 1 dependent step)
    {
        float4 A0[8], A1[8];
        #pragma unroll
        for (int q = 0; q < 8; ++q) {
            int l12 = id[q] - 4095;                       // level-12 position
            const float4* a = (const float4*)(ws + AUX0_F + (size_t)l12 * 8);
            A0[q] = a[0]; A1[q] = a[1];
        }
        #pragma unroll
        for (int q = 0; q < 8; ++q) {
            float ss = s[q];
            float v13 = A0[q].x;
            bool b0 = ss > v13; ss = b0 ? ss - v13 : ss;
            float v14 = b0 ? A0[q].z : A0[q].y;
            bool b1 = ss > v14; ss = b1 ? ss - v14 : ss;
            float v15 = b1 ? (b0 ? A1[q].z : A1[q].x)
                           : (b0 ? A1[q].y : A0[q].w);
            bool b2 = ss > v15; ss = b2 ? ss - v15 : ss;
            s[q]  = ss;
            id[q] = 8 * id[q] + 7 + (b0 ? 4 : 0) + (b1 ? 2 : 0) + (b2 ? 1 : 0);
        }
    }
    // levels 16..18 via one 32B aux1 fetch per chain
    {
        float4 A0[8], A1[8];
        #pragma unroll
        for (int q = 0; q < 8; ++q) {
            int l15 = id[q] - 32767;                      // level-15 position
            const float4* a = (const float4*)(ws + AUX1_F + (size_t)l15 * 8);
            A0[q] = a[0]; A1[q] = a[1];
        }
        #pragma unroll
        for (int q = 0; q < 8; ++q) {
            float ss = s[q];
            float v16 = A0[q].x;
            bool b0 = ss > v16; ss = b0 ? ss - v16 : ss;
            float v17 = b0 ? A0[q].z : A0[q].y;
            bool b1 = ss > v17; ss = b1 ? ss - v17 : ss;
            float v18 = b1 ? (b0 ? A1[q].z : A1[q].x)
                           : (b0 ? A1[q].y : A0[q].w);
            bool b2 = ss > v18; ss = b2 ? ss - v18 : ss;
            s[q]  = ss;
            id[q] = 8 * id[q] + 7 + (b0 ? 4 : 0) + (b1 ? 2 : 0) + (b2 ? 1 : 0);
        }
    }

    // bottom 3 levels from one 32 B leaf load per chain, all in registers
    int res[8];
    #pragma unroll
    for (int g = 0; g < 2; ++g) {                 // two groups of 4 chains
        float4 X[4], Y[4];
        #pragma unroll
        for (int k = 0; k < 4; ++k) {
            int q = 4 * g + k;
            int p = id[q] - L18OFF;               // level-18 position
            const float4* pp = (const float4*)prio + 2 * (size_t)p;
            X[k] = pp[0]; Y[k] = pp[1];           // leaves 8p..8p+7
        }
        #pragma unroll
        for (int k = 0; k < 4; ++k) {
            int q = 4 * g + k;
            int p = id[q] - L18OFF;
            float4 x = X[k], y = Y[k];
            float l19 = (x.x + x.y) + (x.z + x.w);        // level-19 left child
            bool r1 = s[q] > l19;
            float ss = r1 ? s[q] - l19 : s[q];
            float l20 = r1 ? (y.x + y.y) : (x.x + x.y);   // level-20 left child
            bool r2 = ss > l20;
            ss = r2 ? ss - l20 : ss;
            float leaf = r1 ? (r2 ? y.z : y.x) : (r2 ? x.z : x.x);  // left leaf
            bool r3 = ss > leaf;
            res[q] = 8 * p + (r1 ? 4 : 0) + (r2 ? 2 : 0) + (r3 ? 1 : 0);
        }
    }
    *(int4*)(out + j0)     = make_int4(res[0], res[1], res[2], res[3]);
    *(int4*)(out + j0 + 4) = make_int4(res[4], res[5], res[6], res[7]);
}

extern "C" void kernel_launch(void* const* d_in, const int* in_sizes, int n_in,
                              void* d_out, int out_size, void* d_ws, size_t ws_size,
                              hipStream_t stream) {
    const float* prio    = (const float*)d_in[0];   // [CAP]
    const float* uniform = (const float*)d_in[1];   // [NSAMP]
    (void)in_sizes; (void)n_in; (void)out_size; (void)ws_size;

    float* ws = (float*)d_ws;   // 303104 floats used (~1.16 MB)

    build_tree<<<512, 256, 0, stream>>>(prio, ws);
    sample_kernel<<<NSAMP / 2048, 256, 0, stream>>>(ws, prio, uniform, (int*)d_out);
}